// Round 1
// baseline (581.083 us; speedup 1.0000x reference)
//
#include <hip/hip_runtime.h>

// SDF Chamfer loss, H=W=64, 2 images.
// ws layout (floats):
//   [0   .. 127]  chamfer partial sums: ((img*2+dir)*32 + tile_block)
//   [128 .. 255]  mask-count partials:  ((img*2+set)*32 + tile_block)
//   [256 .. 257]  L1 |p-g| sums per img
//   [512 .. ]     points, float2 [img][set][NP], coords poisoned to SENT if unmasked

#define HH 64
#define WW 64
#define NV ((HH-1)*WW)   // 4032 vertical edges
#define NHE (HH*(WW-1))  // 4032 horizontal edges
#define NP (NV+NHE)      // 8064 points per (img,set)
#define EPSF 1e-8f
#define SENT 1e8f
#define PTS_OFF 512

__device__ __forceinline__ float block_reduce_sum(float v) {
    // 256 threads = 4 waves of 64
    for (int o = 32; o > 0; o >>= 1) v += __shfl_down(v, o, 64);
    __shared__ float red[4];
    int lane = threadIdx.x & 63, wid = threadIdx.x >> 6;
    if (lane == 0) red[wid] = v;
    __syncthreads();
    if (wid == 0) {
        v = (lane < 4) ? red[lane] : 0.f;
        v += __shfl_down(v, 2, 64);
        v += __shfl_down(v, 1, 64);
    }
    return v; // valid in thread 0
}

// grid: 128 blocks = (img*2+set)*32 + tile, 256 threads
__global__ void extract_kernel(const float* __restrict__ pred,
                               const float* __restrict__ gt,
                               float* __restrict__ ws) {
    int blk = blockIdx.x;
    int imgset = blk >> 5;          // img*2 + set
    int b = imgset >> 1, set = imgset & 1;
    int e = ((blk & 31) << 8) + threadIdx.x;
    const float* sdf = (set == 0 ? pred : gt) + b * (HH * WW);
    float2* pts = (float2*)(ws + PTS_OFF) + imgset * NP;

    int m = 0;
    if (e < NP) {
        float v1, v2, R, C;
        if (e < NV) {                       // vertical: between rows i and i+1
            int i = e >> 6, j = e & 63;     // W=64
            v1 = sdf[i * WW + j];
            v2 = sdf[(i + 1) * WW + j];
            float a = fabsf(v1) / (fabsf(v1) + fabsf(v2) + EPSF);
            float frac = (v1 == 0.f) ? 0.f : ((v2 == 0.f) ? 1.f : a);
            R = (float)i + frac; C = (float)j;
        } else {                            // horizontal: between cols j and j+1
            int eh = e - NV;
            int i = eh / (WW - 1), j = eh % (WW - 1);
            v1 = sdf[i * WW + j];
            v2 = sdf[i * WW + j + 1];
            float a = fabsf(v1) / (fabsf(v1) + fabsf(v2) + EPSF);
            float frac = (v1 == 0.f) ? 0.f : ((v2 == 0.f) ? 1.f : a);
            R = (float)i; C = (float)j + frac;
        }
        m = (v1 == 0.f) || (v2 == 0.f) || (v1 * v2 < 0.f);
        if (!m) { R = SENT; C = SENT; }     // poison: never wins a min
        pts[e] = make_float2(R, C);
    }

    // masked count for this block
    unsigned long long ball = __ballot(m != 0);
    __shared__ int cnt_s[4];
    int wid = threadIdx.x >> 6;
    if ((threadIdx.x & 63) == 0) cnt_s[wid] = __popcll(ball);
    __syncthreads();
    if (threadIdx.x == 0) {
        ws[128 + imgset * 32 + (blk & 31)] =
            (float)(cnt_s[0] + cnt_s[1] + cnt_s[2] + cnt_s[3]);
    }
}

// grid: 2 blocks (one per img), 256 threads
__global__ void l1_kernel(const float* __restrict__ pred,
                          const float* __restrict__ gt,
                          float* __restrict__ ws) {
    int b = blockIdx.x;
    const float* p = pred + b * (HH * WW);
    const float* g = gt + b * (HH * WW);
    float s = 0.f;
    for (int i = threadIdx.x; i < HH * WW; i += 256)
        s += fabsf(p[i] - g[i]);
    s = block_reduce_sum(s);
    if (threadIdx.x == 0) ws[256 + b] = s;
}

// grid: 128 blocks = (img*2+dir)*32 + tile, 256 threads
// dir 0: p from pred, candidates gt (-> mean1)
// dir 1: p from gt,  candidates pred (-> mean2)
__global__ void chamfer_kernel(float* __restrict__ ws) {
    int blk = blockIdx.x;
    int imgdir = blk >> 5;
    int b = imgdir >> 1, dir = imgdir & 1;
    int e = ((blk & 31) << 8) + threadIdx.x;
    const float2* pts_all = (const float2*)(ws + PTS_OFF);
    const float2* P = pts_all + (b * 2 + dir) * NP;
    const float2* G = pts_all + (b * 2 + (1 - dir)) * NP;

    float pR = SENT, pC = SENT;
    if (e < NP) { float2 t = P[e]; pR = t.x; pC = t.y; }

    __shared__ float2 tile[256];
    float minsq = 3.0e38f;
    for (int t0 = 0; t0 < NP; t0 += 256) {
        if (t0) __syncthreads();
        int idx = t0 + threadIdx.x;
        tile[threadIdx.x] = (idx < NP) ? G[idx] : make_float2(1e9f, 1e9f);
        __syncthreads();
        #pragma unroll 16
        for (int k = 0; k < 256; ++k) {
            float dx = pR - tile[k].x;
            float dy = pC - tile[k].y;
            float d2 = dx * dx + dy * dy;
            minsq = fminf(minsq, d2);
        }
    }

    float d = sqrtf(minsq);
    float wgt = (pR < 1e7f) ? 1.f : 0.f;   // recover mask from sentinel
    float c = wgt * d;                      // 0 for unmasked / out-of-range p
    __syncthreads();
    c = block_reduce_sum(c);
    if (threadIdx.x == 0) ws[imgdir * 32 + (blk & 31)] = c;
}

// 1 thread
__global__ void finalize_kernel(const float* __restrict__ ws,
                                float* __restrict__ out) {
    float loss = 0.f;
    for (int b = 0; b < 2; ++b) {
        float s0 = 0.f, s1 = 0.f, c0 = 0.f, c1 = 0.f;
        for (int t = 0; t < 32; ++t) {
            s0 += ws[(b * 2 + 0) * 32 + t];
            s1 += ws[(b * 2 + 1) * 32 + t];
            c0 += ws[128 + (b * 2 + 0) * 32 + t];
            c1 += ws[128 + (b * 2 + 1) * 32 + t];
        }
        float mean1 = s0 / fmaxf(c0, 1.f);  // pred->gt, weighted by pred mask
        float mean2 = s1 / fmaxf(c1, 1.f);  // gt->pred, weighted by gt mask
        float cd = -mean1 + mean2;
        float l1 = ws[256 + b] * (1.f / (HH * WW));
        loss += l1 + fabsf(cd);
    }
    out[0] = loss * 0.5f;
}

extern "C" void kernel_launch(void* const* d_in, const int* in_sizes, int n_in,
                              void* d_out, int out_size, void* d_ws, size_t ws_size,
                              hipStream_t stream) {
    const float* pred = (const float*)d_in[0];
    const float* gt   = (const float*)d_in[1];
    float* ws  = (float*)d_ws;
    float* out = (float*)d_out;

    hipLaunchKernelGGL(extract_kernel, dim3(128), dim3(256), 0, stream, pred, gt, ws);
    hipLaunchKernelGGL(l1_kernel,      dim3(2),   dim3(256), 0, stream, pred, gt, ws);
    hipLaunchKernelGGL(chamfer_kernel, dim3(128), dim3(256), 0, stream, ws);
    hipLaunchKernelGGL(finalize_kernel, dim3(1),  dim3(1),   0, stream, ws, out);
}

// Round 2
// 41.180 us; speedup vs baseline: 14.1109x; 14.1109x over previous
//
#include <hip/hip_runtime.h>

// SDF Chamfer loss, H=W=64, 2 images.
// ws layout (floats):
//   [0   .. 127]  chamfer partial sums: ((img*2+dir)*32 + ptile)
//   [128 .. 255]  mask-count partials:  ((img*2+set)*32 + tile)
//   [256 .. 257]  L1 |p-g| sums per img
//   [260 .. 260+4*NP)   per-point min d2 (uint-ordered floats, atomicMin)
//   [32768 .. ]   points, float2 [img][set][NP], coords poisoned if unmasked

#define HH 64
#define WW 64
#define NV ((HH-1)*WW)   // 4032 vertical edges
#define NHE (HH*(WW-1))  // 4032 horizontal edges
#define NP (NV+NHE)      // 8064 points per (img,set)
#define EPSF 1e-8f
#define SENT 1e8f
#define BIGF 3.0e38f
#define PM_OFF 260
#define PTS_OFF 32768
#define NSLICE 16
#define SLICE (NP/NSLICE)   // 504

__device__ __forceinline__ float block_reduce_sum(float v) {
    for (int o = 32; o > 0; o >>= 1) v += __shfl_down(v, o, 64);
    __shared__ float red[4];
    int lane = threadIdx.x & 63, wid = threadIdx.x >> 6;
    if (lane == 0) red[wid] = v;
    __syncthreads();
    if (wid == 0) {
        v = (lane < 4) ? red[lane] : 0.f;
        v += __shfl_down(v, 2, 64);
        v += __shfl_down(v, 1, 64);
    }
    return v; // valid in thread 0
}

// grid: 128 blocks = (img*2+set)*32 + tile, 256 threads
__global__ void extract_kernel(const float* __restrict__ pred,
                               const float* __restrict__ gt,
                               float* __restrict__ ws) {
    int blk = blockIdx.x;
    int imgset = blk >> 5;          // img*2 + set
    int b = imgset >> 1, set = imgset & 1;
    int e = ((blk & 31) << 8) + threadIdx.x;
    const float* sdf = (set == 0 ? pred : gt) + b * (HH * WW);
    float2* pts = (float2*)(ws + PTS_OFF) + imgset * NP;

    int m = 0;
    if (e < NP) {
        ws[PM_OFF + imgset * NP + e] = BIGF;   // init per-point min
        float v1, v2, R, C;
        if (e < NV) {                       // vertical: rows i, i+1
            int i = e >> 6, j = e & 63;
            v1 = sdf[i * WW + j];
            v2 = sdf[(i + 1) * WW + j];
            float a = fabsf(v1) / (fabsf(v1) + fabsf(v2) + EPSF);
            float frac = (v1 == 0.f) ? 0.f : ((v2 == 0.f) ? 1.f : a);
            R = (float)i + frac; C = (float)j;
        } else {                            // horizontal: cols j, j+1
            int eh = e - NV;
            int i = eh / (WW - 1), j = eh % (WW - 1);
            v1 = sdf[i * WW + j];
            v2 = sdf[i * WW + j + 1];
            float a = fabsf(v1) / (fabsf(v1) + fabsf(v2) + EPSF);
            float frac = (v1 == 0.f) ? 0.f : ((v2 == 0.f) ? 1.f : a);
            R = (float)i; C = (float)j + frac;
        }
        m = (v1 == 0.f) || (v2 == 0.f) || (v1 * v2 < 0.f);
        if (!m) { R = SENT; C = SENT; }     // poison: never wins a min
        pts[e] = make_float2(R, C);
    }

    unsigned long long ball = __ballot(m != 0);
    __shared__ int cnt_s[4];
    int wid = threadIdx.x >> 6;
    if ((threadIdx.x & 63) == 0) cnt_s[wid] = __popcll(ball);
    __syncthreads();
    if (threadIdx.x == 0) {
        ws[128 + imgset * 32 + (blk & 31)] =
            (float)(cnt_s[0] + cnt_s[1] + cnt_s[2] + cnt_s[3]);
    }
}

// grid: 2 blocks, 256 threads
__global__ void l1_kernel(const float* __restrict__ pred,
                          const float* __restrict__ gt,
                          float* __restrict__ ws) {
    int b = blockIdx.x;
    const float* p = pred + b * (HH * WW);
    const float* g = gt + b * (HH * WW);
    float s = 0.f;
    for (int i = threadIdx.x; i < HH * WW; i += 256)
        s += fabsf(p[i] - g[i]);
    s = block_reduce_sum(s);
    if (threadIdx.x == 0) ws[256 + b] = s;
}

// grid: 4 imgdir * 32 ptile * NSLICE slices, 256 threads.
// imgdir = img*2+dir; P-set index == imgdir, candidate set = imgdir^1.
__global__ void chamfer_kernel(float* __restrict__ ws) {
    int blk = blockIdx.x;
    int slice = blk & (NSLICE - 1);
    int ptile = (blk >> 4) & 31;
    int imgdir = blk >> 9;
    int e = (ptile << 8) + threadIdx.x;
    const float2* pts_all = (const float2*)(ws + PTS_OFF);
    const float2* P = pts_all + imgdir * NP;
    const float2* G = pts_all + (imgdir ^ 1) * NP + slice * SLICE;

    float pR = SENT, pC = SENT;
    if (e < NP) { float2 t = P[e]; pR = t.x; pC = t.y; }

    __shared__ __align__(16) float2 tile[SLICE];
    for (int i = threadIdx.x; i < SLICE; i += 256) tile[i] = G[i];
    __syncthreads();

    const float4* t4 = (const float4*)tile;
    float m0 = BIGF, m1 = BIGF, m2 = BIGF, m3 = BIGF;
    #pragma unroll 4
    for (int k = 0; k < SLICE / 4; ++k) {     // 4 candidates/iter, indep chains
        float4 a = t4[2 * k];
        float4 c = t4[2 * k + 1];
        float dx0 = pR - a.x, dy0 = pC - a.y;
        float dx1 = pR - a.z, dy1 = pC - a.w;
        float dx2 = pR - c.x, dy2 = pC - c.y;
        float dx3 = pR - c.z, dy3 = pC - c.w;
        m0 = fminf(m0, __builtin_fmaf(dx0, dx0, dy0 * dy0));
        m1 = fminf(m1, __builtin_fmaf(dx1, dx1, dy1 * dy1));
        m2 = fminf(m2, __builtin_fmaf(dx2, dx2, dy2 * dy2));
        m3 = fminf(m3, __builtin_fmaf(dx3, dx3, dy3 * dy3));
    }
    float m = fminf(fminf(m0, m1), fminf(m2, m3));

    if (e < NP) {
        unsigned* pm = (unsigned*)(ws + PM_OFF) + imgdir * NP + e;
        atomicMin(pm, __float_as_uint(m));   // exact for non-negative floats
    }
}

// grid: 4*32 blocks, 256 threads: sqrt + weighted sum of per-point mins
__global__ void reduce_kernel(float* __restrict__ ws) {
    int blk = blockIdx.x;
    int imgdir = blk >> 5;
    int e = ((blk & 31) << 8) + threadIdx.x;
    const float2* P = (const float2*)(ws + PTS_OFF) + imgdir * NP;
    float c = 0.f;
    if (e < NP) {
        float d2 = ws[PM_OFF + imgdir * NP + e];
        float w = (P[e].x < 1e7f) ? 1.f : 0.f;
        c = w * sqrtf(d2);
    }
    c = block_reduce_sum(c);
    if (threadIdx.x == 0) ws[imgdir * 32 + (blk & 31)] = c;
}

// 1 thread
__global__ void finalize_kernel(const float* __restrict__ ws,
                                float* __restrict__ out) {
    float loss = 0.f;
    for (int b = 0; b < 2; ++b) {
        float s0 = 0.f, s1 = 0.f, c0 = 0.f, c1 = 0.f;
        for (int t = 0; t < 32; ++t) {
            s0 += ws[(b * 2 + 0) * 32 + t];
            s1 += ws[(b * 2 + 1) * 32 + t];
            c0 += ws[128 + (b * 2 + 0) * 32 + t];
            c1 += ws[128 + (b * 2 + 1) * 32 + t];
        }
        float mean1 = s0 / fmaxf(c0, 1.f);
        float mean2 = s1 / fmaxf(c1, 1.f);
        float cd = -mean1 + mean2;
        float l1 = ws[256 + b] * (1.f / (HH * WW));
        loss += l1 + fabsf(cd);
    }
    out[0] = loss * 0.5f;
}

extern "C" void kernel_launch(void* const* d_in, const int* in_sizes, int n_in,
                              void* d_out, int out_size, void* d_ws, size_t ws_size,
                              hipStream_t stream) {
    const float* pred = (const float*)d_in[0];
    const float* gt   = (const float*)d_in[1];
    float* ws  = (float*)d_ws;
    float* out = (float*)d_out;

    hipLaunchKernelGGL(extract_kernel, dim3(128), dim3(256), 0, stream, pred, gt, ws);
    hipLaunchKernelGGL(l1_kernel,      dim3(2),   dim3(256), 0, stream, pred, gt, ws);
    hipLaunchKernelGGL(chamfer_kernel, dim3(4 * 32 * NSLICE), dim3(256), 0, stream, ws);
    hipLaunchKernelGGL(reduce_kernel,  dim3(128), dim3(256), 0, stream, ws);
    hipLaunchKernelGGL(finalize_kernel, dim3(1),  dim3(1),   0, stream, ws, out);
}

// Round 3
// 39.381 us; speedup vs baseline: 14.7555x; 1.0457x over previous
//
#include <hip/hip_runtime.h>

// SDF Chamfer loss, H=W=64, 2 images. Compacted-point brute force.
// ws float layout:
//   [0..3]      int: compacted point counts per imgset (memset 0 each call)
//   [16..143]   l1 partial sums, one per extract block (128)
//   [256..256+4*NP)   per-point min d^2 (float bits, atomicMin on uint)
//   [33024..)   compacted points float2 [imgset][NP]
#define HH 64
#define WW 64
#define NV ((HH-1)*WW)   // 4032
#define NHE (HH*(WW-1))  // 4032
#define NP (NV+NHE)      // 8064
#define EPSF 1e-8f
#define BIGF 3.0e38f
#define NSLICE 32
#define SLICE (NP/NSLICE)   // 252
#define CNT_OFF 0
#define L1_OFF 16
#define MIN_OFF 256
#define PTS_OFF 33024

// grid: 128 blocks = imgset(4) x 32 tiles, 256 threads. Extract + compact + l1.
__global__ void extract_l1_kernel(const float* __restrict__ pred,
                                  const float* __restrict__ gt,
                                  float* __restrict__ ws) {
    int blk = blockIdx.x;
    int imgset = blk >> 5;          // img*2 + set
    int b = imgset >> 1, set = imgset & 1;
    int e = ((blk & 31) << 8) + threadIdx.x;
    const float* sdf = (set == 0 ? pred : gt) + b * (HH * WW);

    if (e < NP) {
        // init per-point min (indexed by compacted position, covers [0,NP))
        ((unsigned*)(ws + MIN_OFF))[imgset * NP + e] = __float_as_uint(BIGF);
        float v1, v2, R, C;
        if (e < NV) {                       // vertical: rows i, i+1
            int i = e >> 6, j = e & 63;
            v1 = sdf[i * WW + j];
            v2 = sdf[(i + 1) * WW + j];
            float a = fabsf(v1) / (fabsf(v1) + fabsf(v2) + EPSF);
            float frac = (v1 == 0.f) ? 0.f : ((v2 == 0.f) ? 1.f : a);
            R = (float)i + frac; C = (float)j;
        } else {                            // horizontal: cols j, j+1
            int eh = e - NV;
            int i = eh / (WW - 1), j = eh % (WW - 1);
            v1 = sdf[i * WW + j];
            v2 = sdf[i * WW + j + 1];
            float a = fabsf(v1) / (fabsf(v1) + fabsf(v2) + EPSF);
            float frac = (v1 == 0.f) ? 0.f : ((v2 == 0.f) ? 1.f : a);
            R = (float)i; C = (float)j + frac;
        }
        bool m = (v1 == 0.f) || (v2 == 0.f) || (v1 * v2 < 0.f);
        if (m) {   // stream-compact masked points (order-independent downstream)
            int pos = atomicAdd((int*)ws + CNT_OFF + imgset, 1);
            ((float2*)(ws + PTS_OFF))[imgset * NP + pos] = make_float2(R, C);
        }
    }

    // L1 term: 64 pixels per block over flat [2*4096] images
    float s = 0.f;
    if (threadIdx.x < 64) {
        int px = blk * 64 + threadIdx.x;
        s = fabsf(pred[px] - gt[px]);
    }
    for (int o = 32; o; o >>= 1) s += __shfl_down(s, o, 64);
    if (threadIdx.x == 0) ws[L1_OFF + blk] = s;
}

// grid: 4 imgset * 32 ptile * 32 slice = 4096 blocks, 256 threads.
// P = compacted set imgset (queries), G = compacted set imgset^1 (candidates).
__global__ void chamfer_kernel(float* __restrict__ ws) {
    int blk = blockIdx.x;
    int slice = blk & 31;
    int ptile = (blk >> 5) & 31;
    int imgset = blk >> 10;
    const int* cnts = (const int*)ws;
    int cntP = cnts[imgset];
    int cntG = cnts[imgset ^ 1];
    if (ptile * 256 >= cntP || slice * SLICE >= cntG) return;

    const float2* P = (const float2*)(ws + PTS_OFF) + imgset * NP;
    const float2* G = (const float2*)(ws + PTS_OFF) + (imgset ^ 1) * NP;

    int e = ptile * 256 + threadIdx.x;
    bool valid = e < cntP;
    float pR = 1e8f, pC = 1e8f;
    if (valid) { float2 t = P[e]; pR = t.x; pC = t.y; }

    __shared__ __align__(16) float2 tile[SLICE];
    if (threadIdx.x < SLICE) {
        int idx = slice * SLICE + threadIdx.x;
        tile[threadIdx.x] = (idx < cntG) ? G[idx] : make_float2(1e9f, 1e9f);
    }
    __syncthreads();

    const float4* t4 = (const float4*)tile;
    float m0 = BIGF, m1 = BIGF, m2 = BIGF, m3 = BIGF;
    #pragma unroll 3
    for (int k = 0; k < SLICE / 4; ++k) {     // 4 candidates/iter
        float4 a = t4[2 * k];
        float4 c = t4[2 * k + 1];
        float dx0 = pR - a.x, dy0 = pC - a.y;
        float dx1 = pR - a.z, dy1 = pC - a.w;
        float dx2 = pR - c.x, dy2 = pC - c.y;
        float dx3 = pR - c.z, dy3 = pC - c.w;
        m0 = fminf(m0, __builtin_fmaf(dx0, dx0, dy0 * dy0));
        m1 = fminf(m1, __builtin_fmaf(dx1, dx1, dy1 * dy1));
        m2 = fminf(m2, __builtin_fmaf(dx2, dx2, dy2 * dy2));
        m3 = fminf(m3, __builtin_fmaf(dx3, dx3, dy3 * dy3));
    }
    float m = fminf(fminf(m0, m1), fminf(m2, m3));

    if (valid) {
        unsigned* pm = (unsigned*)(ws + MIN_OFF) + imgset * NP + e;
        atomicMin(pm, __float_as_uint(m));   // exact for non-negative floats
    }
}

// 1 block, 1024 threads: per-direction sqrt-sums + l1 + final loss.
__global__ void tail_kernel(const float* __restrict__ ws,
                            float* __restrict__ out) {
    __shared__ float red[16];
    const int* cnts = (const int*)ws;
    int lane = threadIdx.x & 63, wid = threadIdx.x >> 6;

    float sums[4];
    for (int d = 0; d < 4; ++d) {
        int cnt = cnts[d];
        float s = 0.f;
        for (int e = threadIdx.x; e < cnt; e += 1024)
            s += sqrtf(ws[MIN_OFF + d * NP + e]);
        for (int o = 32; o; o >>= 1) s += __shfl_down(s, o, 64);
        __syncthreads();
        if (lane == 0) red[wid] = s;
        __syncthreads();
        if (wid == 0) {
            s = (lane < 16) ? red[lane] : 0.f;
            for (int o = 8; o; o >>= 1) s += __shfl_down(s, o, 64);
        }
        sums[d] = s;   // valid in thread 0
    }

    float l1v = (threadIdx.x < 128) ? ws[L1_OFF + threadIdx.x] : 0.f;
    float l1s[2];
    for (int b = 0; b < 2; ++b) {
        float s = (wid == (b ? 1 : 0)) ? l1v : 0.f;   // threads [b*64,(b+1)*64)
        for (int o = 32; o; o >>= 1) s += __shfl_down(s, o, 64);
        __syncthreads();
        if (lane == 0) red[wid] = s;
        __syncthreads();
        if (wid == 0) {
            s = (lane < 16) ? red[lane] : 0.f;
            for (int o = 8; o; o >>= 1) s += __shfl_down(s, o, 64);
        }
        l1s[b] = s;
    }

    if (threadIdx.x == 0) {
        float loss = 0.f;
        for (int b = 0; b < 2; ++b) {
            float mean1 = sums[b * 2 + 0] / fmaxf((float)cnts[b * 2 + 0], 1.f);
            float mean2 = sums[b * 2 + 1] / fmaxf((float)cnts[b * 2 + 1], 1.f);
            float cd = -mean1 + mean2;
            loss += l1s[b] * (1.f / (HH * WW)) + fabsf(cd);
        }
        out[0] = loss * 0.5f;
    }
}

extern "C" void kernel_launch(void* const* d_in, const int* in_sizes, int n_in,
                              void* d_out, int out_size, void* d_ws, size_t ws_size,
                              hipStream_t stream) {
    const float* pred = (const float*)d_in[0];
    const float* gt   = (const float*)d_in[1];
    float* ws  = (float*)d_ws;
    float* out = (float*)d_out;

    hipMemsetAsync(ws, 0, 16, stream);   // zero the 4 compaction counters
    hipLaunchKernelGGL(extract_l1_kernel, dim3(128), dim3(256), 0, stream, pred, gt, ws);
    hipLaunchKernelGGL(chamfer_kernel, dim3(4 * 32 * NSLICE), dim3(256), 0, stream, ws);
    hipLaunchKernelGGL(tail_kernel, dim3(1), dim3(1024), 0, stream, ws, out);
}